// Round 2
// baseline (1042.232 us; speedup 1.0000x reference)
//
#include <hip/hip_runtime.h>
#include <stdint.h>

// SparseDiffAttn: o_cache = o_dense - o_sparse(top-896 keys per 192-query group)
// B=1, H=24, N=3072, D=128, BM=192, QG=16, TK=896. fp32 in/out.
//
// Identity: with pn_ij = exp(z_ij)/Z_i, o_sparse = (sum_{j in S} pn v_j)/(sum_{j in S} pn).
// kA: Z (2-way split, 3 MFMA). kB: o_dense + per-chunk colsums (3-way split, 6 MFMA
// -> z error ~2e-7, below fp32-reference noise, so top-k ranking is stable).
// kC: exact top-k set w/ jax tie semantics. kD: o_S and rho, out -= o_S/rho.

#define H 24
#define N 3072
#define DH 128
#define SCALE 0.08838834764831845f  // 1/sqrt(128)
#define TK 896

typedef __attribute__((ext_vector_type(8))) short short8;   // 8 bf16
typedef __attribute__((ext_vector_type(4))) float f32x4;

__device__ __forceinline__ uint32_t bf_rne(float x){
  uint32_t u = __float_as_uint(x);
  return (u + 0x7FFFu + ((u >> 16) & 1u)) >> 16;
}

__device__ __forceinline__ f32x4 f4zero(){ f32x4 z = {0.f,0.f,0.f,0.f}; return z; }

// 2-way RNE split: q = h + l + O(2^-17 q)
__device__ __forceinline__ void split8_2(const float* f, uint4& h4, uint4& l4){
  uint32_t hw[4], lw[4];
#pragma unroll
  for (int i = 0; i < 4; i++){
    float a = f[2*i], b = f[2*i+1];
    uint32_t ha = bf_rne(a), hb = bf_rne(b);
    float ra = a - __uint_as_float(ha << 16);
    float rb = b - __uint_as_float(hb << 16);
    hw[i] = ha | (hb << 16);
    lw[i] = bf_rne(ra) | (bf_rne(rb) << 16);
  }
  h4.x = hw[0]; h4.y = hw[1]; h4.z = hw[2]; h4.w = hw[3];
  l4.x = lw[0]; l4.y = lw[1]; l4.z = lw[2]; l4.w = lw[3];
}

// 3-way RNE split: q = h + m + l + O(2^-24 q)  (full fp32 mantissa)
__device__ __forceinline__ void split8_3(const float* f, uint4& h4, uint4& m4, uint4& l4){
  uint32_t hw[4], mw[4], lw[4];
#pragma unroll
  for (int i = 0; i < 4; i++){
    float a = f[2*i], b = f[2*i+1];
    uint32_t ha = bf_rne(a), hb = bf_rne(b);
    float ra = a - __uint_as_float(ha << 16);
    float rb = b - __uint_as_float(hb << 16);
    uint32_t ma = bf_rne(ra), mb = bf_rne(rb);
    float la = ra - __uint_as_float(ma << 16);
    float lb = rb - __uint_as_float(mb << 16);
    hw[i] = ha | (hb << 16);
    mw[i] = ma | (mb << 16);
    lw[i] = bf_rne(la) | (bf_rne(lb) << 16);
  }
  h4.x = hw[0]; h4.y = hw[1]; h4.z = hw[2]; h4.w = hw[3];
  m4.x = mw[0]; m4.y = mw[1]; m4.z = mw[2]; m4.w = mw[3];
  l4.x = lw[0]; l4.y = lw[1]; l4.z = lw[2]; l4.w = lw[3];
}

__device__ __forceinline__ short8 as_s8(const uint4 u){
  union { uint4 u4; short8 s; } t; t.u4 = u; return t.s;
}

// 1152 blocks = 8 XCD * (3 heads * 48 chunks); same-head chunks share an XCD
__device__ __forceinline__ void mapHC(int bid, int& h, int& ch){
  int x = bid & 7;
  int i = bid >> 3;        // 0..143
  h = x + 8 * (i / 48);    // 0..23
  ch = i % 48;             // 64-row chunk within head
}

// per-wave Q fragments (prescaled by SCALE), 2-way split
__device__ __forceinline__ void load_qfrags2(const float* qhead, int R, int w, int lane,
                                             uint4* qh, uint4* ql){
  int row = R + w*16 + (lane & 15);
  const float* qp = qhead + (size_t)row * DH;
#pragma unroll
  for (int s = 0; s < 4; s++){
    int d0 = s*32 + (lane >> 4)*8;
    float4 a = *(const float4*)(qp + d0);
    float4 b = *(const float4*)(qp + d0 + 4);
    float f[8] = {a.x*SCALE, a.y*SCALE, a.z*SCALE, a.w*SCALE,
                  b.x*SCALE, b.y*SCALE, b.z*SCALE, b.w*SCALE};
    split8_2(f, qh[s], ql[s]);
  }
}

// per-wave Q fragments (prescaled by SCALE), 3-way split
__device__ __forceinline__ void load_qfrags3(const float* qhead, int R, int w, int lane,
                                             uint4* qh, uint4* qm, uint4* ql){
  int row = R + w*16 + (lane & 15);
  const float* qp = qhead + (size_t)row * DH;
#pragma unroll
  for (int s = 0; s < 4; s++){
    int d0 = s*32 + (lane >> 4)*8;
    float4 a = *(const float4*)(qp + d0);
    float4 b = *(const float4*)(qp + d0 + 4);
    float f[8] = {a.x*SCALE, a.y*SCALE, a.z*SCALE, a.w*SCALE,
                  b.x*SCALE, b.y*SCALE, b.z*SCALE, b.w*SCALE};
    split8_3(f, qh[s], qm[s], ql[s]);
  }
}

// stage one K row-slice (16 d-values) into XOR-swizzled bf16 LDS tiles (2 tiers)
__device__ __forceinline__ void stage_k2(const float* kp, char* khi, char* klo,
                                         int jst, int dblk){
  float4 a = *(const float4*)(kp);
  float4 b = *(const float4*)(kp + 4);
  float4 c = *(const float4*)(kp + 8);
  float4 d = *(const float4*)(kp + 12);
  float f0[8] = {a.x,a.y,a.z,a.w,b.x,b.y,b.z,b.w};
  float f1[8] = {c.x,c.y,c.z,c.w,d.x,d.y,d.z,d.w};
  uint4 h4, l4;
  int base = jst*256 + dblk*32;
  int sw = (jst & 7) << 4;
  split8_2(f0, h4, l4);
  *(uint4*)(khi + (base ^ sw)) = h4;
  *(uint4*)(klo + (base ^ sw)) = l4;
  split8_2(f1, h4, l4);
  *(uint4*)(khi + ((base + 16) ^ sw)) = h4;
  *(uint4*)(klo + ((base + 16) ^ sw)) = l4;
}

// same, 3 tiers
__device__ __forceinline__ void stage_k3(const float* kp, char* khi, char* kmi, char* klo,
                                         int jst, int dblk){
  float4 a = *(const float4*)(kp);
  float4 b = *(const float4*)(kp + 4);
  float4 c = *(const float4*)(kp + 8);
  float4 d = *(const float4*)(kp + 12);
  float f0[8] = {a.x,a.y,a.z,a.w,b.x,b.y,b.z,b.w};
  float f1[8] = {c.x,c.y,c.z,c.w,d.x,d.y,d.z,d.w};
  uint4 h4, m4, l4;
  int base = jst*256 + dblk*32;
  int sw = (jst & 7) << 4;
  split8_3(f0, h4, m4, l4);
  *(uint4*)(khi + (base ^ sw)) = h4;
  *(uint4*)(kmi + (base ^ sw)) = m4;
  *(uint4*)(klo + (base ^ sw)) = l4;
  split8_3(f1, h4, m4, l4);
  *(uint4*)(khi + ((base + 16) ^ sw)) = h4;
  *(uint4*)(kmi + ((base + 16) ^ sw)) = m4;
  *(uint4*)(klo + ((base + 16) ^ sw)) = l4;
}

// stage one V row-slice transposed: vts[d][j], pitch 80 B
__device__ __forceinline__ void stage_v(const float* vp, char* vts, int jv, int dv){
  float4 a = *(const float4*)(vp);
  float4 b = *(const float4*)(vp + 4);
  float4 c = *(const float4*)(vp + 8);
  float4 d = *(const float4*)(vp + 12);
  float f[16] = {a.x,a.y,a.z,a.w,b.x,b.y,b.z,b.w,c.x,c.y,c.z,c.w,d.x,d.y,d.z,d.w};
#pragma unroll
  for (int i = 0; i < 16; i++)
    *(unsigned short*)(vts + (size_t)(dv + i)*80 + jv*2) = (unsigned short)bf_rne(f[i]);
}

// z[16x32] via 2-way split (hl + lh + hh), fp32 MFMA accumulate
__device__ __forceinline__ void zcompute3(const char* khi, const char* klo,
                                          const uint4* qh, const uint4* ql,
                                          int lane, f32x4* zac){
  zac[0] = f4zero();
  zac[1] = f4zero();
#pragma unroll
  for (int s = 0; s < 4; s++){
    short8 qa = as_s8(qh[s]);
    short8 qb = as_s8(ql[s]);
#pragma unroll
    for (int ct = 0; ct < 2; ct++){
      int key = ct*16 + (lane & 15);
      int off = (key*256 + (s*32 + (lane >> 4)*8)*2) ^ ((key & 7) << 4);
      short8 kh = *(const short8*)(khi + off);
      short8 kl = *(const short8*)(klo + off);
      zac[ct] = __builtin_amdgcn_mfma_f32_16x16x32_bf16(qa, kl, zac[ct], 0, 0, 0);
      zac[ct] = __builtin_amdgcn_mfma_f32_16x16x32_bf16(qb, kh, zac[ct], 0, 0, 0);
      zac[ct] = __builtin_amdgcn_mfma_f32_16x16x32_bf16(qa, kh, zac[ct], 0, 0, 0);
    }
  }
}

// z[16x32] via 3-way split (mm + hl + lh + hm + mh + hh): z error ~2e-7 unbiased
__device__ __forceinline__ void zcompute6(const char* khi, const char* kmi, const char* klo,
                                          const uint4* qh, const uint4* qm, const uint4* ql,
                                          int lane, f32x4* zac){
  zac[0] = f4zero();
  zac[1] = f4zero();
#pragma unroll
  for (int s = 0; s < 4; s++){
    short8 qa = as_s8(qh[s]);
    short8 qb = as_s8(qm[s]);
    short8 qc = as_s8(ql[s]);
#pragma unroll
    for (int ct = 0; ct < 2; ct++){
      int key = ct*16 + (lane & 15);
      int off = (key*256 + (s*32 + (lane >> 4)*8)*2) ^ ((key & 7) << 4);
      short8 kh = *(const short8*)(khi + off);
      short8 km = *(const short8*)(kmi + off);
      short8 kl = *(const short8*)(klo + off);
      zac[ct] = __builtin_amdgcn_mfma_f32_16x16x32_bf16(qb, km, zac[ct], 0, 0, 0);
      zac[ct] = __builtin_amdgcn_mfma_f32_16x16x32_bf16(qa, kl, zac[ct], 0, 0, 0);
      zac[ct] = __builtin_amdgcn_mfma_f32_16x16x32_bf16(qc, kh, zac[ct], 0, 0, 0);
      zac[ct] = __builtin_amdgcn_mfma_f32_16x16x32_bf16(qa, km, zac[ct], 0, 0, 0);
      zac[ct] = __builtin_amdgcn_mfma_f32_16x16x32_bf16(qb, kh, zac[ct], 0, 0, 0);
      zac[ct] = __builtin_amdgcn_mfma_f32_16x16x32_bf16(qa, kh, zac[ct], 0, 0, 0);
    }
  }
}

// ---------------- kernel A: row sums Z_i = sum_j exp(z_ij) ----------------
__global__ __launch_bounds__(256, 2) void kA(const float* __restrict__ qg,
                                             const float* __restrict__ kg,
                                             float* __restrict__ Zg){
  __shared__ alignas(16) char khi[32*256];
  __shared__ alignas(16) char klo[32*256];
  int h, ch; mapHC(blockIdx.x, h, ch);
  const int tid = threadIdx.x, w = tid >> 6, lane = tid & 63;
  const int l15 = lane & 15, l4 = lane >> 4;
  const int R = ch * 64;
  const float* qhead = qg + (size_t)h*N*DH;
  const float* khead = kg + (size_t)h*N*DH;
  uint4 qh[4], ql[4];
  load_qfrags2(qhead, R, w, lane, qh, ql);
  float zs[4] = {0.f,0.f,0.f,0.f};
  const int jst = tid >> 3, dblk = tid & 7;
  for (int kt = 0; kt < 96; kt++){
    stage_k2(khead + (size_t)(kt*32 + jst)*DH + dblk*16, khi, klo, jst, dblk);
    __syncthreads();
    f32x4 zac[2];
    zcompute3(khi, klo, qh, ql, lane, zac);
#pragma unroll
    for (int ct = 0; ct < 2; ct++)
#pragma unroll
      for (int r = 0; r < 4; r++)
        zs[r] += __expf(zac[ct][r]);
    __syncthreads();
  }
#pragma unroll
  for (int m = 1; m < 16; m <<= 1)
#pragma unroll
    for (int r = 0; r < 4; r++)
      zs[r] += __shfl_xor(zs[r], m);
  if (l15 == 0){
#pragma unroll
    for (int r = 0; r < 4; r++)
      Zg[h*N + R + w*16 + l4*4 + r] = zs[r];
  }
}

// ---- kernel B: o_dense (normalized, fp32 acc) + per-chunk colsum partials ----
__global__ __launch_bounds__(256, 2) void kB(const float* __restrict__ qg,
                                             const float* __restrict__ kg,
                                             const float* __restrict__ vg,
                                             const float* __restrict__ Zg,
                                             float* __restrict__ cpart,
                                             float* __restrict__ outg){
  __shared__ alignas(16) char khi[32*256];
  __shared__ alignas(16) char kmi[32*256];
  __shared__ alignas(16) char klo[32*256];
  __shared__ alignas(16) char vts[128*80];
  __shared__ alignas(16) char pls[4][16*80];
  __shared__ float colbuf[4][32];
  int h, ch; mapHC(blockIdx.x, h, ch);
  const int tid = threadIdx.x, w = tid >> 6, lane = tid & 63;
  const int l15 = lane & 15, l4 = lane >> 4;
  const int R = ch * 64;
  const float* qhead = qg + (size_t)h*N*DH;
  const float* khead = kg + (size_t)h*N*DH;
  const float* vhead = vg + (size_t)h*N*DH;
  uint4 qh[4], qm[4], ql[4];
  load_qfrags3(qhead, R, w, lane, qh, qm, ql);
  float rz[4];
#pragma unroll
  for (int r = 0; r < 4; r++)
    rz[r] = 1.0f / Zg[h*N + R + w*16 + l4*4 + r];
  f32x4 oac[8];
#pragma unroll
  for (int i = 0; i < 8; i++) oac[i] = f4zero();
  const int jst = tid >> 3, dblk = tid & 7;
  const int jv = tid & 31, dv = (tid >> 5) * 16;
  float* cp = cpart + (size_t)(h*48 + ch) * 3072;
  for (int kt = 0; kt < 96; kt++){
    if (kt > 0 && tid < 32)
      cp[(kt-1)*32 + tid] = colbuf[0][tid] + colbuf[1][tid] + colbuf[2][tid] + colbuf[3][tid];
    stage_k3(khead + (size_t)(kt*32 + jst)*DH + dblk*16, khi, kmi, klo, jst, dblk);
    stage_v(vhead + (size_t)(kt*32 + jv)*DH + dv, vts, jv, dv);
    __syncthreads();
    f32x4 zac[2];
    zcompute6(khi, kmi, klo, qh, qm, ql, lane, zac);
    float pn[2][4];
#pragma unroll
    for (int ct = 0; ct < 2; ct++)
#pragma unroll
      for (int r = 0; r < 4; r++)
        pn[ct][r] = __expf(zac[ct][r]) * rz[r];
    // colsum over this wave's 16 rows (fp32, deterministic combine via colbuf)
#pragma unroll
    for (int ct = 0; ct < 2; ct++){
      float cs = pn[ct][0] + pn[ct][1] + pn[ct][2] + pn[ct][3];
      cs += __shfl_xor(cs, 16);
      cs += __shfl_xor(cs, 32);
      if (lane < 16) colbuf[w][ct*16 + lane] = cs;
    }
    // P -> bf16 LDS (wave-local), then PV MFMA
    char* pw = pls[w];
#pragma unroll
    for (int ct = 0; ct < 2; ct++)
#pragma unroll
      for (int r = 0; r < 4; r++)
        *(unsigned short*)(pw + (size_t)(l4*4 + r)*80 + (ct*16 + l15)*2) =
            (unsigned short)bf_rne(pn[ct][r]);
    short8 ap = *(const short8*)(pw + (size_t)l15*80 + l4*16);
#pragma unroll
    for (int vt = 0; vt < 8; vt++){
      short8 vb = *(const short8*)(vts + (size_t)(vt*16 + l15)*80 + l4*16);
      oac[vt] = __builtin_amdgcn_mfma_f32_16x16x32_bf16(ap, vb, oac[vt], 0, 0, 0);
    }
    __syncthreads();
  }
  if (tid < 32)
    cp[95*32 + tid] = colbuf[0][tid] + colbuf[1][tid] + colbuf[2][tid] + colbuf[3][tid];
#pragma unroll
  for (int vt = 0; vt < 8; vt++)
#pragma unroll
    for (int r = 0; r < 4; r++)
      outg[((size_t)h*N + R + w*16 + l4*4 + r)*DH + vt*16 + l15] = oac[vt][r];
}

// ------------- kernel C: per-group top-896 (jax.lax.top_k set semantics) -------------
__global__ __launch_bounds__(256, 2) void kC(const float* __restrict__ cpart,
                                             int* __restrict__ selg){
  __shared__ uint32_t cu[3072];
  __shared__ int red[4];
  __shared__ int runS;
  const int gid = blockIdx.x;           // 0..383 = h*16 + g
  const int h = gid >> 4, g = gid & 15;
  const int tid = threadIdx.x, w = tid >> 6, lane = tid & 63;
  const float* p0 = cpart + (size_t)(h*48 + g*3) * 3072;
  const float* p1 = p0 + 3072;
  const float* p2 = p0 + 6144;
  for (int i = tid; i < 3072; i += 256)
    cu[i] = __float_as_uint(p0[i] + p1[i] + p2[i]);   // colsums > 0 -> bit-monotonic
  __syncthreads();
  uint32_t lo = 0u, hi = 0xFFFFFFFFu;   // V = max{T : count(cu >= T) >= TK}
  for (int it = 0; it < 32; it++){
    bool active = (lo < hi);
    uint32_t mid = (uint32_t)(((uint64_t)lo + (uint64_t)hi + 1ull) >> 1);
    int c = 0;
    if (active){
      for (int i = tid; i < 3072; i += 256) c += (cu[i] >= mid) ? 1 : 0;
#pragma unroll
      for (int m = 1; m < 64; m <<= 1) c += __shfl_xor(c, m);
    }
    if (lane == 0) red[w] = c;
    __syncthreads();
    int tot = red[0] + red[1] + red[2] + red[3];
    __syncthreads();
    if (active){ if (tot >= TK) lo = mid; else hi = mid - 1; }
  }
  const uint32_t V = lo;
  {
    int c = 0;
    for (int i = tid; i < 3072; i += 256) c += (cu[i] > V) ? 1 : 0;
#pragma unroll
    for (int m = 1; m < 64; m <<= 1) c += __shfl_xor(c, m);
    if (lane == 0) red[w] = c;
  }
  __syncthreads();
  const int ngt = red[0] + red[1] + red[2] + red[3];
  const int need = TK - ngt;            // ties to take, ascending index
  int* sb = selg + (size_t)gid * TK;
  if (tid == 0) runS = 0;
  __syncthreads();
  for (int ck = 0; ck < 12; ck++){
    int j = ck*256 + tid;
    bool f = (cu[j] > V);
    unsigned long long bal = __ballot(f);
    int wpre = __popcll(bal & ((1ull << lane) - 1ull));
    int wtot = __popcll(bal);
    if (lane == 0) red[w] = wtot;
    __syncthreads();
    int woff = 0;
    for (int x = 0; x < w; x++) woff += red[x];
    int base = runS;
    if (f) sb[base + woff + wpre] = j;
    __syncthreads();
    if (tid == 0) runS = base + red[0] + red[1] + red[2] + red[3];
    __syncthreads();
  }
  if (tid == 0) runS = 0;
  __syncthreads();
  for (int ck = 0; ck < 12; ck++){
    int j = ck*256 + tid;
    bool f = (cu[j] == V);
    unsigned long long bal = __ballot(f);
    int wpre = __popcll(bal & ((1ull << lane) - 1ull));
    int wtot = __popcll(bal);
    if (lane == 0) red[w] = wtot;
    __syncthreads();
    int woff = 0;
    for (int x = 0; x < w; x++) woff += red[x];
    int base = runS;
    int rank = base + woff + wpre;
    if (f && rank < need) sb[ngt + rank] = j;
    __syncthreads();
    if (tid == 0) runS = base + red[0] + red[1] + red[2] + red[3];
    __syncthreads();
  }
}

// ------- kernel D: o_S, rho over selected keys; out -= o_S/rho (in place) -------
__global__ __launch_bounds__(256, 2) void kD(const float* __restrict__ qg,
                                             const float* __restrict__ kg,
                                             const float* __restrict__ vg,
                                             const float* __restrict__ Zg,
                                             const int* __restrict__ selg,
                                             float* __restrict__ outg){
  __shared__ alignas(16) char khi[32*256];
  __shared__ alignas(16) char klo[32*256];
  __shared__ alignas(16) char vts[128*80];
  __shared__ alignas(16) char pls[4][16*80];
  __shared__ int sell[TK];
  int h, ch; mapHC(blockIdx.x, h, ch);
  const int tid = threadIdx.x, w = tid >> 6, lane = tid & 63;
  const int l15 = lane & 15, l4 = lane >> 4;
  const int R = ch * 64;
  const int g = ch / 3;
  const float* qhead = qg + (size_t)h*N*DH;
  const float* khead = kg + (size_t)h*N*DH;
  const float* vhead = vg + (size_t)h*N*DH;
  const int* sb = selg + (size_t)(h*16 + g) * TK;
  for (int i = tid; i < TK; i += 256) sell[i] = sb[i];
  uint4 qh[4], ql[4];
  load_qfrags2(qhead, R, w, lane, qh, ql);
  float rz[4];
#pragma unroll
  for (int r = 0; r < 4; r++)
    rz[r] = 1.0f / Zg[h*N + R + w*16 + l4*4 + r];
  f32x4 oac[8];
#pragma unroll
  for (int i = 0; i < 8; i++) oac[i] = f4zero();
  float rh[4] = {0.f,0.f,0.f,0.f};
  const int jst = tid >> 3, dblk = tid & 7;
  const int jv = tid & 31, dv = (tid >> 5) * 16;
  __syncthreads();
  for (int st = 0; st < 28; st++){
    {
      int key = sell[st*32 + jst];
      stage_k2(khead + (size_t)key*DH + dblk*16, khi, klo, jst, dblk);
    }
    {
      int key = sell[st*32 + jv];
      stage_v(vhead + (size_t)key*DH + dv, vts, jv, dv);
    }
    __syncthreads();
    f32x4 zac[2];
    zcompute3(khi, klo, qh, ql, lane, zac);
    float pn[2][4];
#pragma unroll
    for (int ct = 0; ct < 2; ct++)
#pragma unroll
      for (int r = 0; r < 4; r++){
        pn[ct][r] = __expf(zac[ct][r]) * rz[r];
        rh[r] += pn[ct][r];
      }
    char* pw = pls[w];
#pragma unroll
    for (int ct = 0; ct < 2; ct++)
#pragma unroll
      for (int r = 0; r < 4; r++)
        *(unsigned short*)(pw + (size_t)(l4*4 + r)*80 + (ct*16 + l15)*2) =
            (unsigned short)bf_rne(pn[ct][r]);
    short8 ap = *(const short8*)(pw + (size_t)l15*80 + l4*16);
#pragma unroll
    for (int vt = 0; vt < 8; vt++){
      short8 vb = *(const short8*)(vts + (size_t)(vt*16 + l15)*80 + l4*16);
      oac[vt] = __builtin_amdgcn_mfma_f32_16x16x32_bf16(ap, vb, oac[vt], 0, 0, 0);
    }
    __syncthreads();
  }
#pragma unroll
  for (int m = 1; m < 16; m <<= 1)
#pragma unroll
    for (int r = 0; r < 4; r++)
      rh[r] += __shfl_xor(rh[r], m);
  float ri[4];
#pragma unroll
  for (int r = 0; r < 4; r++) ri[r] = 1.0f / rh[r];
#pragma unroll
  for (int vt = 0; vt < 8; vt++)
#pragma unroll
    for (int r = 0; r < 4; r++){
      size_t idx = ((size_t)h*N + R + w*16 + l4*4 + r)*DH + vt*16 + l15;
      outg[idx] = outg[idx] - oac[vt][r]*ri[r];
    }
}

extern "C" void kernel_launch(void* const* d_in, const int* in_sizes, int n_in,
                              void* d_out, int out_size, void* d_ws, size_t ws_size,
                              hipStream_t stream){
  (void)in_sizes; (void)n_in; (void)out_size; (void)ws_size;
  const float* q = (const float*)d_in[0];
  const float* k = (const float*)d_in[1];
  const float* v = (const float*)d_in[2];
  float* out = (float*)d_out;
  // ws layout: Z[24*3072] f32 | cpart[1152*3072] f32 | sel[384*896] i32  (~15.8 MB)
  float* Z = (float*)d_ws;
  float* cpart = Z + (size_t)H * N;
  int* sel = (int*)(cpart + (size_t)1152 * 3072);
  kA<<<dim3(1152), dim3(256), 0, stream>>>(q, k, Z);
  kB<<<dim3(1152), dim3(256), 0, stream>>>(q, k, v, Z, cpart, out);
  kC<<<dim3(384),  dim3(256), 0, stream>>>(cpart, sel);
  kD<<<dim3(1152), dim3(256), 0, stream>>>(q, k, v, Z, sel, out);
}